// Round 1
// baseline (4568.312 us; speedup 1.0000x reference)
//
#include <hip/hip_runtime.h>

namespace {

struct Combine9 { const float* W[9]; const float* S[9]; float* O[9]; };

// Wc[512x256] = W[512x256] @ wsh[256x256]
__global__ __launch_bounds__(256) void combine_weights(Combine9 a) {
  int combo = blockIdx.y;
  int r = blockIdx.x;        // 0..511
  int c = threadIdx.x;       // 0..255
  const float* W = a.W[combo];
  const float* S = a.S[combo];
  float acc = 0.f;
  #pragma unroll 4
  for (int k = 0; k < 256; ++k) acc = fmaf(W[r * 256 + k], S[k * 256 + c], acc);
  a.O[combo][r * 256 + c] = acc;
}

struct Gemm3 { const float* A[3]; const float* B[3]; float* C[3]; int M[3]; };

// C[M x 256] = A[M x 512] @ B[512 x 256], 64x64 tile, 256 threads, 4x4 micro
__global__ __launch_bounds__(256) void proj_gemm(Gemm3 g) {
  int z = blockIdx.z;
  const float* __restrict__ A = g.A[z];
  const float* __restrict__ B = g.B[z];
  float* __restrict__ C = g.C[z];
  int M = g.M[z];
  int row0 = blockIdx.y * 64;
  if (row0 >= M) return;
  int col0 = blockIdx.x * 64;
  __shared__ __align__(16) float As[16][68];
  __shared__ __align__(16) float Bs[16][64];
  int tid = threadIdx.x;
  int tx = tid & 15, ty = tid >> 4;
  int la_r = tid >> 2, la_k = (tid & 3) << 2;
  int lb_k = tid >> 4, lb_c = (tid & 15) << 2;
  int ar = row0 + la_r;
  float acc[4][4] = {};
  for (int k0 = 0; k0 < 512; k0 += 16) {
    float4 av = make_float4(0.f, 0.f, 0.f, 0.f);
    if (ar < M) av = *(const float4*)(A + (size_t)ar * 512 + k0 + la_k);
    As[la_k + 0][la_r] = av.x;
    As[la_k + 1][la_r] = av.y;
    As[la_k + 2][la_r] = av.z;
    As[la_k + 3][la_r] = av.w;
    *(float4*)&Bs[lb_k][lb_c] = *(const float4*)(B + (size_t)(k0 + lb_k) * 256 + col0 + lb_c);
    __syncthreads();
    #pragma unroll
    for (int kk = 0; kk < 16; ++kk) {
      float4 a4 = *(const float4*)&As[kk][ty << 2];
      float4 b4 = *(const float4*)&Bs[kk][tx << 2];
      float av_[4] = {a4.x, a4.y, a4.z, a4.w};
      float bv_[4] = {b4.x, b4.y, b4.z, b4.w};
      #pragma unroll
      for (int i = 0; i < 4; ++i)
        #pragma unroll
        for (int j = 0; j < 4; ++j)
          acc[i][j] = fmaf(av_[i], bv_[j], acc[i][j]);
    }
    __syncthreads();
  }
  #pragma unroll
  for (int i = 0; i < 4; ++i) {
    int r = row0 + (ty << 2) + i;
    if (r < M) {
      float4 v = make_float4(acc[i][0], acc[i][1], acc[i][2], acc[i][3]);
      *(float4*)(C + (size_t)r * 256 + col0 + (tx << 2)) = v;
    }
  }
}

struct Scatter2 {
  const float* proj[2];
  const int* src[2];
  const int* dst[2];
  const float* w[2];
  float* nbft;   // [2][n][256]
  int nE;
  int n;
};

// one wave per edge: 64 lanes x float4 = 256 floats
__global__ __launch_bounds__(256) void scatter_add(Scatter2 s) {
  int rel = blockIdx.y;
  int e = blockIdx.x * 4 + (threadIdx.x >> 6);
  if (e >= s.nE) return;
  int lane = threadIdx.x & 63;
  int sidx = s.src[rel][e];
  int didx = s.dst[rel][e];
  float wt = s.w[rel][e];
  float4 v = *(const float4*)(s.proj[rel] + (size_t)sidx * 256 + (lane << 2));
  float* o = s.nbft + ((size_t)rel * s.n + didx) * 256 + (lane << 2);
  atomicAdd(o + 0, v.x * wt);
  atomicAdd(o + 1, v.y * wt);
  atomicAdd(o + 2, v.z * wt);
  atomicAdd(o + 3, v.w * wt);
}

// e_out[rel*n + i] = leaky_relu(dot(nbft[rel][i], watt[0:256]) + dot(self[i], watt[256:512]))
__global__ __launch_bounds__(256) void e_dots(const float* __restrict__ nbft,
                                              const float* __restrict__ selfft,
                                              const float* __restrict__ watt,
                                              float* __restrict__ e_out, int n) {
  int idx = blockIdx.x * 4 + (threadIdx.x >> 6);
  if (idx >= 2 * n) return;
  int lane = threadIdx.x & 63;
  int i = idx < n ? idx : idx - n;
  float4 v  = *(const float4*)(nbft + (size_t)idx * 256 + (lane << 2));
  float4 sv = *(const float4*)(selfft + (size_t)i * 256 + (lane << 2));
  float4 wa = *(const float4*)(watt + (lane << 2));
  float4 wb = *(const float4*)(watt + 256 + (lane << 2));
  float sum = v.x * wa.x + v.y * wa.y + v.z * wa.z + v.w * wa.w +
              sv.x * wb.x + sv.y * wb.y + sv.z * wb.z + sv.w * wb.w;
  #pragma unroll
  for (int off = 32; off > 0; off >>= 1) sum += __shfl_down(sum, off, 64);
  if (lane == 0) e_out[idx] = sum > 0.f ? sum : 0.01f * sum;
}

// faithful reshape semantics: att row i = softmax(e_flat[2i], e_flat[2i+1])
__global__ void att_kernel(const float* __restrict__ e_flat, float* __restrict__ att, int n) {
  int i = blockIdx.x * blockDim.x + threadIdx.x;
  if (i >= n) return;
  float f0 = e_flat[2 * i], f1 = e_flat[2 * i + 1];
  float m = fmaxf(f0, f1);
  float a = expf(f0 - m), b = expf(f1 - m);
  float inv = 1.f / (a + b);
  att[2 * i] = a * inv;
  att[2 * i + 1] = b * inv;
}

// out[M x 256] = [agg | self] @ wcat[512 x 256] + bias, A built on the fly
__global__ __launch_bounds__(256) void final_gemm(
    const float* __restrict__ nbft, const float* __restrict__ selfft,
    const float* __restrict__ att, const float* __restrict__ wcat,
    const float* __restrict__ bias, float* __restrict__ out, int M) {
  int row0 = blockIdx.y * 64;
  if (row0 >= M) return;
  int col0 = blockIdx.x * 64;
  __shared__ __align__(16) float As[16][68];
  __shared__ __align__(16) float Bs[16][64];
  int tid = threadIdx.x;
  int tx = tid & 15, ty = tid >> 4;
  int la_r = tid >> 2, la_k = (tid & 3) << 2;
  int lb_k = tid >> 4, lb_c = (tid & 15) << 2;
  int ar = row0 + la_r;
  float a0 = 0.f, a1 = 0.f;
  if (ar < M) {
    float2 at = *(const float2*)(att + 2 * ar);
    a0 = at.x; a1 = at.y;
  }
  float acc[4][4] = {};
  for (int k0 = 0; k0 < 512; k0 += 16) {
    float4 av = make_float4(0.f, 0.f, 0.f, 0.f);
    int kg = k0 + la_k;
    if (ar < M) {
      if (kg < 256) {
        float4 v0 = *(const float4*)(nbft + (size_t)ar * 256 + kg);
        float4 v1 = *(const float4*)(nbft + ((size_t)M + ar) * 256 + kg);
        av.x = fmaf(v0.x, a0, v1.x * a1);
        av.y = fmaf(v0.y, a0, v1.y * a1);
        av.z = fmaf(v0.z, a0, v1.z * a1);
        av.w = fmaf(v0.w, a0, v1.w * a1);
      } else {
        av = *(const float4*)(selfft + (size_t)ar * 256 + (kg - 256));
      }
    }
    As[la_k + 0][la_r] = av.x;
    As[la_k + 1][la_r] = av.y;
    As[la_k + 2][la_r] = av.z;
    As[la_k + 3][la_r] = av.w;
    *(float4*)&Bs[lb_k][lb_c] = *(const float4*)(wcat + (size_t)(k0 + lb_k) * 256 + col0 + lb_c);
    __syncthreads();
    #pragma unroll
    for (int kk = 0; kk < 16; ++kk) {
      float4 a4 = *(const float4*)&As[kk][ty << 2];
      float4 b4 = *(const float4*)&Bs[kk][tx << 2];
      float av_[4] = {a4.x, a4.y, a4.z, a4.w};
      float bv_[4] = {b4.x, b4.y, b4.z, b4.w};
      #pragma unroll
      for (int i = 0; i < 4; ++i)
        #pragma unroll
        for (int j = 0; j < 4; ++j)
          acc[i][j] = fmaf(av_[i], bv_[j], acc[i][j]);
    }
    __syncthreads();
  }
  float4 bb = *(const float4*)(bias + col0 + (tx << 2));
  #pragma unroll
  for (int i = 0; i < 4; ++i) {
    int r = row0 + (ty << 2) + i;
    if (r < M) {
      float4 v = make_float4(acc[i][0] + bb.x, acc[i][1] + bb.y,
                             acc[i][2] + bb.z, acc[i][3] + bb.w);
      *(float4*)(out + (size_t)r * 256 + col0 + (tx << 2)) = v;
    }
  }
}

} // namespace

extern "C" void kernel_launch(void* const* d_in, const int* in_sizes, int n_in,
                              void* d_out, int out_size, void* d_ws, size_t ws_size,
                              hipStream_t stream) {
  (void)in_sizes; (void)n_in; (void)out_size; (void)ws_size;
  const float* x[3] = {(const float*)d_in[0], (const float*)d_in[1], (const float*)d_in[2]};

  // workspace layout (floats): total 24,299,648 floats = 97.2 MB
  float* ws = (float*)d_ws;
  float* Wc     = ws;                                  // 9*512*256
  float* selfb  = Wc + (size_t)9 * 512 * 256;          // 20000*256 max
  float* projb  = selfb + (size_t)20000 * 256;         // 30000*256 max
  float* nbftb  = projb + (size_t)30000 * 256;         // 2*20000*256 max
  float* e_buf  = nbftb + (size_t)2 * 20000 * 256;     // 40000 max
  float* att_buf = e_buf + 40000;                      // 40000 max

  // ---- combined weights: Wc[t*3+{0,1}] = W_t_nb @ wsh_t ; Wc[t*3+2] = ws_t @ wsh_t
  Combine9 c9;
  for (int t = 0; t < 3; ++t) {
    int wb = 21 + t * 7;
    const float* wsh = (const float*)d_in[wb + 3];
    c9.W[t * 3 + 0] = (const float*)d_in[wb + 0];
    c9.W[t * 3 + 1] = (const float*)d_in[wb + 1];
    c9.W[t * 3 + 2] = (const float*)d_in[wb + 2];
    for (int j = 0; j < 3; ++j) {
      c9.S[t * 3 + j] = wsh;
      c9.O[t * 3 + j] = Wc + (size_t)(t * 3 + j) * 512 * 256;
    }
  }
  combine_weights<<<dim3(512, 9), 256, 0, stream>>>(c9);

  const int n_of[3] = {20000, 10000, 5000};
  const int nbt[3][2] = {{1, 2}, {0, 2}, {0, 1}};   // neighbor type ids in reference order
  const int ebase[3][2] = {{3, 6}, {9, 12}, {15, 18}};
  const int nE[3] = {320000, 160000, 80000};
  const size_t out_off[3] = {0, (size_t)20000 * 256, (size_t)30000 * 256};

  for (int t = 0; t < 3; ++t) {
    int n = n_of[t];
    int wb = 21 + t * 7;
    int nb0 = nbt[t][0], nb1 = nbt[t][1];
    int m0 = n_of[nb0], m1 = n_of[nb1];

    // projections (2 neighbor rels + self), batched over grid.z
    Gemm3 g;
    g.A[0] = x[nb0]; g.B[0] = Wc + (size_t)(t * 3 + 0) * 512 * 256; g.C[0] = projb;                     g.M[0] = m0;
    g.A[1] = x[nb1]; g.B[1] = Wc + (size_t)(t * 3 + 1) * 512 * 256; g.C[1] = projb + (size_t)m0 * 256;  g.M[1] = m1;
    g.A[2] = x[t];   g.B[2] = Wc + (size_t)(t * 3 + 2) * 512 * 256; g.C[2] = selfb;                     g.M[2] = n;
    int maxM = m0 > m1 ? m0 : m1; if (n > maxM) maxM = n;
    proj_gemm<<<dim3(4, (maxM + 63) / 64, 3), 256, 0, stream>>>(g);

    // zero nbft, then edge scatter (both relations via grid.y)
    hipMemsetAsync(nbftb, 0, (size_t)2 * n * 256 * sizeof(float), stream);
    Scatter2 s;
    s.proj[0] = projb;
    s.proj[1] = projb + (size_t)m0 * 256;
    for (int r = 0; r < 2; ++r) {
      int eb = ebase[t][r];
      s.src[r] = (const int*)d_in[eb];
      s.dst[r] = (const int*)d_in[eb + 1];
      s.w[r]   = (const float*)d_in[eb + 2];
    }
    s.nbft = nbftb; s.nE = nE[t]; s.n = n;
    scatter_add<<<dim3((nE[t] + 3) / 4, 2), 256, 0, stream>>>(s);

    // attention scores + softmax (faithful reshape semantics)
    e_dots<<<dim3((2 * n + 3) / 4), 256, 0, stream>>>(nbftb, selfb, (const float*)d_in[wb + 4], e_buf, n);
    att_kernel<<<dim3((n + 255) / 256), 256, 0, stream>>>(e_buf, att_buf, n);

    // fused [agg | self] @ wcat + bias
    final_gemm<<<dim3(4, (n + 63) / 64), 256, 0, stream>>>(
        nbftb, selfb, att_buf, (const float*)d_in[wb + 5], (const float*)d_in[wb + 6],
        (float*)d_out + out_off[t], n);
  }
}

// Round 2
// 1268.636 us; speedup vs baseline: 3.6010x; 3.6010x over previous
//
#include <hip/hip_runtime.h>

namespace {

struct Combine9 { const float* W[9]; const float* S[9]; float* O[9]; };

// Wc[512x256] = W[512x256] @ wsh[256x256]
__global__ __launch_bounds__(256) void combine_weights(Combine9 a) {
  int combo = blockIdx.y;
  int r = blockIdx.x;        // 0..511
  int c = threadIdx.x;       // 0..255
  const float* W = a.W[combo];
  const float* S = a.S[combo];
  float acc = 0.f;
  #pragma unroll 4
  for (int k = 0; k < 256; ++k) acc = fmaf(W[r * 256 + k], S[k * 256 + c], acc);
  a.O[combo][r * 256 + c] = acc;
}

struct Gemm3 { const float* A[3]; const float* B[3]; float* C[3]; int M[3]; };

// C[M x 256] = A[M x 512] @ B[512 x 256], 64x64 tile, 256 threads, 4x4 micro
__global__ __launch_bounds__(256) void proj_gemm(Gemm3 g) {
  int z = blockIdx.z;
  const float* __restrict__ A = g.A[z];
  const float* __restrict__ B = g.B[z];
  float* __restrict__ C = g.C[z];
  int M = g.M[z];
  int row0 = blockIdx.y * 64;
  if (row0 >= M) return;
  int col0 = blockIdx.x * 64;
  __shared__ __align__(16) float As[16][68];
  __shared__ __align__(16) float Bs[16][64];
  int tid = threadIdx.x;
  int tx = tid & 15, ty = tid >> 4;
  int la_r = tid >> 2, la_k = (tid & 3) << 2;
  int lb_k = tid >> 4, lb_c = (tid & 15) << 2;
  int ar = row0 + la_r;
  float acc[4][4] = {};
  for (int k0 = 0; k0 < 512; k0 += 16) {
    float4 av = make_float4(0.f, 0.f, 0.f, 0.f);
    if (ar < M) av = *(const float4*)(A + (size_t)ar * 512 + k0 + la_k);
    As[la_k + 0][la_r] = av.x;
    As[la_k + 1][la_r] = av.y;
    As[la_k + 2][la_r] = av.z;
    As[la_k + 3][la_r] = av.w;
    *(float4*)&Bs[lb_k][lb_c] = *(const float4*)(B + (size_t)(k0 + lb_k) * 256 + col0 + lb_c);
    __syncthreads();
    #pragma unroll
    for (int kk = 0; kk < 16; ++kk) {
      float4 a4 = *(const float4*)&As[kk][ty << 2];
      float4 b4 = *(const float4*)&Bs[kk][tx << 2];
      float av_[4] = {a4.x, a4.y, a4.z, a4.w};
      float bv_[4] = {b4.x, b4.y, b4.z, b4.w};
      #pragma unroll
      for (int i = 0; i < 4; ++i)
        #pragma unroll
        for (int j = 0; j < 4; ++j)
          acc[i][j] = fmaf(av_[i], bv_[j], acc[i][j]);
    }
    __syncthreads();
  }
  #pragma unroll
  for (int i = 0; i < 4; ++i) {
    int r = row0 + (ty << 2) + i;
    if (r < M) {
      float4 v = make_float4(acc[i][0], acc[i][1], acc[i][2], acc[i][3]);
      *(float4*)(C + (size_t)r * 256 + col0 + (tx << 2)) = v;
    }
  }
}

struct EdgePair { const int* src[2]; const int* dst[2]; const float* w[2]; int nE; };

__global__ __launch_bounds__(256) void hist_kernel(EdgePair ep, int* __restrict__ counts, int n) {
  int rel = blockIdx.y;
  int e = blockIdx.x * 256 + threadIdx.x;
  if (e >= ep.nE) return;
  atomicAdd(&counts[rel * n + ep.dst[rel][e]], 1);
}

// one block per rel: exclusive scan of counts -> offs; counts becomes cursor
__global__ __launch_bounds__(256) void scan_kernel(int* __restrict__ counts,
                                                   int* __restrict__ offs, int n) {
  int rel = blockIdx.x;
  int* cnt = counts + rel * n;
  int* of = offs + rel * (n + 1);
  __shared__ int tmp[256];
  int running = 0;
  for (int chunk = 0; chunk < n; chunk += 256) {
    int i = chunk + threadIdx.x;
    int v = (i < n) ? cnt[i] : 0;
    tmp[threadIdx.x] = v;
    __syncthreads();
    #pragma unroll
    for (int off = 1; off < 256; off <<= 1) {
      int t = (threadIdx.x >= off) ? tmp[threadIdx.x - off] : 0;
      __syncthreads();
      tmp[threadIdx.x] += t;
      __syncthreads();
    }
    int incl = tmp[threadIdx.x];
    if (i < n) {
      of[i] = running + incl - v;
      cnt[i] = running + incl - v;  // becomes cursor for fill
    }
    int tot = tmp[255];
    __syncthreads();
    running += tot;
  }
  if (threadIdx.x == 0) of[n] = running;
}

__global__ __launch_bounds__(256) void fill_kernel(EdgePair ep, int* __restrict__ cursor,
                                                   int* __restrict__ csr_src,
                                                   float* __restrict__ csr_w, int n, int maxE) {
  int rel = blockIdx.y;
  int e = blockIdx.x * 256 + threadIdx.x;
  if (e >= ep.nE) return;
  int d = ep.dst[rel][e];
  int pos = atomicAdd(&cursor[rel * n + d], 1);
  csr_src[rel * maxE + pos] = ep.src[rel][e];
  csr_w[rel * maxE + pos] = ep.w[rel][e];
}

// one wave per (dst node, rel): register accumulate over its edge bucket, one write
__global__ __launch_bounds__(256) void gather_csr(const float* __restrict__ proj0,
                                                  const float* __restrict__ proj1,
                                                  const int* __restrict__ offs,
                                                  const int* __restrict__ csr_src,
                                                  const float* __restrict__ csr_w,
                                                  int maxE, float* __restrict__ nbft, int n) {
  int rel = blockIdx.y;
  int d = blockIdx.x * 4 + (threadIdx.x >> 6);
  if (d >= n) return;
  int lane = threadIdx.x & 63;
  const float* __restrict__ proj = rel ? proj1 : proj0;
  const int* of = offs + rel * (n + 1);
  int s0 = of[d], s1 = of[d + 1];
  const int* esrc = csr_src + (size_t)rel * maxE;
  const float* ew = csr_w + (size_t)rel * maxE;
  float4 acc0 = make_float4(0.f, 0.f, 0.f, 0.f);
  float4 acc1 = make_float4(0.f, 0.f, 0.f, 0.f);
  int e = s0;
  for (; e + 1 < s1; e += 2) {
    int sA = esrc[e], sB = esrc[e + 1];
    float wA = ew[e], wB = ew[e + 1];
    float4 vA = *(const float4*)(proj + (size_t)sA * 256 + (lane << 2));
    float4 vB = *(const float4*)(proj + (size_t)sB * 256 + (lane << 2));
    acc0.x = fmaf(vA.x, wA, acc0.x); acc0.y = fmaf(vA.y, wA, acc0.y);
    acc0.z = fmaf(vA.z, wA, acc0.z); acc0.w = fmaf(vA.w, wA, acc0.w);
    acc1.x = fmaf(vB.x, wB, acc1.x); acc1.y = fmaf(vB.y, wB, acc1.y);
    acc1.z = fmaf(vB.z, wB, acc1.z); acc1.w = fmaf(vB.w, wB, acc1.w);
  }
  if (e < s1) {
    int sA = esrc[e];
    float wA = ew[e];
    float4 vA = *(const float4*)(proj + (size_t)sA * 256 + (lane << 2));
    acc0.x = fmaf(vA.x, wA, acc0.x); acc0.y = fmaf(vA.y, wA, acc0.y);
    acc0.z = fmaf(vA.z, wA, acc0.z); acc0.w = fmaf(vA.w, wA, acc0.w);
  }
  acc0.x += acc1.x; acc0.y += acc1.y; acc0.z += acc1.z; acc0.w += acc1.w;
  *(float4*)(nbft + ((size_t)rel * n + d) * 256 + (lane << 2)) = acc0;
}

// e_out[rel*n + i] = leaky_relu(dot(nbft[rel][i], watt[0:256]) + dot(self[i], watt[256:512]))
__global__ __launch_bounds__(256) void e_dots(const float* __restrict__ nbft,
                                              const float* __restrict__ selfft,
                                              const float* __restrict__ watt,
                                              float* __restrict__ e_out, int n) {
  int idx = blockIdx.x * 4 + (threadIdx.x >> 6);
  if (idx >= 2 * n) return;
  int lane = threadIdx.x & 63;
  int i = idx < n ? idx : idx - n;
  float4 v  = *(const float4*)(nbft + (size_t)idx * 256 + (lane << 2));
  float4 sv = *(const float4*)(selfft + (size_t)i * 256 + (lane << 2));
  float4 wa = *(const float4*)(watt + (lane << 2));
  float4 wb = *(const float4*)(watt + 256 + (lane << 2));
  float sum = v.x * wa.x + v.y * wa.y + v.z * wa.z + v.w * wa.w +
              sv.x * wb.x + sv.y * wb.y + sv.z * wb.z + sv.w * wb.w;
  #pragma unroll
  for (int off = 32; off > 0; off >>= 1) sum += __shfl_down(sum, off, 64);
  if (lane == 0) e_out[idx] = sum > 0.f ? sum : 0.01f * sum;
}

// faithful reshape semantics: att row i = softmax(e_flat[2i], e_flat[2i+1])
__global__ void att_kernel(const float* __restrict__ e_flat, float* __restrict__ att, int n) {
  int i = blockIdx.x * blockDim.x + threadIdx.x;
  if (i >= n) return;
  float f0 = e_flat[2 * i], f1 = e_flat[2 * i + 1];
  float m = fmaxf(f0, f1);
  float a = expf(f0 - m), b = expf(f1 - m);
  float inv = 1.f / (a + b);
  att[2 * i] = a * inv;
  att[2 * i + 1] = b * inv;
}

// out[M x 256] = [agg | self] @ wcat[512 x 256] + bias, A built on the fly
__global__ __launch_bounds__(256) void final_gemm(
    const float* __restrict__ nbft, const float* __restrict__ selfft,
    const float* __restrict__ att, const float* __restrict__ wcat,
    const float* __restrict__ bias, float* __restrict__ out, int M) {
  int row0 = blockIdx.y * 64;
  if (row0 >= M) return;
  int col0 = blockIdx.x * 64;
  __shared__ __align__(16) float As[16][68];
  __shared__ __align__(16) float Bs[16][64];
  int tid = threadIdx.x;
  int tx = tid & 15, ty = tid >> 4;
  int la_r = tid >> 2, la_k = (tid & 3) << 2;
  int lb_k = tid >> 4, lb_c = (tid & 15) << 2;
  int ar = row0 + la_r;
  float a0 = 0.f, a1 = 0.f;
  if (ar < M) {
    float2 at = *(const float2*)(att + 2 * ar);
    a0 = at.x; a1 = at.y;
  }
  float acc[4][4] = {};
  for (int k0 = 0; k0 < 512; k0 += 16) {
    float4 av = make_float4(0.f, 0.f, 0.f, 0.f);
    int kg = k0 + la_k;
    if (ar < M) {
      if (kg < 256) {
        float4 v0 = *(const float4*)(nbft + (size_t)ar * 256 + kg);
        float4 v1 = *(const float4*)(nbft + ((size_t)M + ar) * 256 + kg);
        av.x = fmaf(v0.x, a0, v1.x * a1);
        av.y = fmaf(v0.y, a0, v1.y * a1);
        av.z = fmaf(v0.z, a0, v1.z * a1);
        av.w = fmaf(v0.w, a0, v1.w * a1);
      } else {
        av = *(const float4*)(selfft + (size_t)ar * 256 + (kg - 256));
      }
    }
    As[la_k + 0][la_r] = av.x;
    As[la_k + 1][la_r] = av.y;
    As[la_k + 2][la_r] = av.z;
    As[la_k + 3][la_r] = av.w;
    *(float4*)&Bs[lb_k][lb_c] = *(const float4*)(wcat + (size_t)(k0 + lb_k) * 256 + col0 + lb_c);
    __syncthreads();
    #pragma unroll
    for (int kk = 0; kk < 16; ++kk) {
      float4 a4 = *(const float4*)&As[kk][ty << 2];
      float4 b4 = *(const float4*)&Bs[kk][tx << 2];
      float av_[4] = {a4.x, a4.y, a4.z, a4.w};
      float bv_[4] = {b4.x, b4.y, b4.z, b4.w};
      #pragma unroll
      for (int i = 0; i < 4; ++i)
        #pragma unroll
        for (int j = 0; j < 4; ++j)
          acc[i][j] = fmaf(av_[i], bv_[j], acc[i][j]);
    }
    __syncthreads();
  }
  float4 bb = *(const float4*)(bias + col0 + (tx << 2));
  #pragma unroll
  for (int i = 0; i < 4; ++i) {
    int r = row0 + (ty << 2) + i;
    if (r < M) {
      float4 v = make_float4(acc[i][0] + bb.x, acc[i][1] + bb.y,
                             acc[i][2] + bb.z, acc[i][3] + bb.w);
      *(float4*)(out + (size_t)r * 256 + col0 + (tx << 2)) = v;
    }
  }
}

} // namespace

extern "C" void kernel_launch(void* const* d_in, const int* in_sizes, int n_in,
                              void* d_out, int out_size, void* d_ws, size_t ws_size,
                              hipStream_t stream) {
  (void)in_sizes; (void)n_in; (void)out_size; (void)ws_size;
  const float* x[3] = {(const float*)d_in[0], (const float*)d_in[1], (const float*)d_in[2]};

  const int MAXE = 320000;

  // workspace layout: 21,819,650 floats = 87.3 MB (ws_size >= 97 MB per R1)
  float* ws = (float*)d_ws;
  float* Wc      = ws;                                   // 9*512*256 = 1,179,648
  float* selfb   = Wc + (size_t)9 * 512 * 256;           // 20000*256 = 5,120,000
  float* dynb    = selfb + (size_t)20000 * 256;          // proj+nbft per type, 14,080,000 max
  float* e_buf   = dynb + (size_t)55000 * 256;           // 40000
  float* att_buf = e_buf + 40000;                        // 40000
  int*   counts  = (int*)(att_buf + 40000);              // 2*20000
  int*   offs    = counts + 40000;                       // 2*20001
  int*   csr_src = offs + 40002;                         // 2*320000
  float* csr_w   = (float*)(csr_src + 2 * MAXE);         // 2*320000

  // ---- combined weights: Wc[t*3+{0,1}] = W_t_nb @ wsh_t ; Wc[t*3+2] = ws_t @ wsh_t
  Combine9 c9;
  for (int t = 0; t < 3; ++t) {
    int wb = 21 + t * 7;
    const float* wsh = (const float*)d_in[wb + 3];
    c9.W[t * 3 + 0] = (const float*)d_in[wb + 0];
    c9.W[t * 3 + 1] = (const float*)d_in[wb + 1];
    c9.W[t * 3 + 2] = (const float*)d_in[wb + 2];
    for (int j = 0; j < 3; ++j) {
      c9.S[t * 3 + j] = wsh;
      c9.O[t * 3 + j] = Wc + (size_t)(t * 3 + j) * 512 * 256;
    }
  }
  combine_weights<<<dim3(512, 9), 256, 0, stream>>>(c9);

  const int n_of[3] = {20000, 10000, 5000};
  const int nbt[3][2] = {{1, 2}, {0, 2}, {0, 1}};   // neighbor type ids in reference order
  const int ebase[3][2] = {{3, 6}, {9, 12}, {15, 18}};
  const int nE[3] = {320000, 160000, 80000};
  const size_t out_off[3] = {0, (size_t)20000 * 256, (size_t)30000 * 256};

  for (int t = 0; t < 3; ++t) {
    int n = n_of[t];
    int wb = 21 + t * 7;
    int nb0 = nbt[t][0], nb1 = nbt[t][1];
    int m0 = n_of[nb0], m1 = n_of[nb1];

    float* projb = dynb;
    float* nbftb = dynb + (size_t)(m0 + m1) * 256;

    // projections (2 neighbor rels + self), batched over grid.z
    Gemm3 g;
    g.A[0] = x[nb0]; g.B[0] = Wc + (size_t)(t * 3 + 0) * 512 * 256; g.C[0] = projb;                     g.M[0] = m0;
    g.A[1] = x[nb1]; g.B[1] = Wc + (size_t)(t * 3 + 1) * 512 * 256; g.C[1] = projb + (size_t)m0 * 256;  g.M[1] = m1;
    g.A[2] = x[t];   g.B[2] = Wc + (size_t)(t * 3 + 2) * 512 * 256; g.C[2] = selfb;                     g.M[2] = n;
    int maxM = m0 > m1 ? m0 : m1; if (n > maxM) maxM = n;
    proj_gemm<<<dim3(4, (maxM + 63) / 64, 3), 256, 0, stream>>>(g);

    // CSR build: histogram -> scan -> fill
    EdgePair ep;
    for (int r = 0; r < 2; ++r) {
      int eb = ebase[t][r];
      ep.src[r] = (const int*)d_in[eb];
      ep.dst[r] = (const int*)d_in[eb + 1];
      ep.w[r]   = (const float*)d_in[eb + 2];
    }
    ep.nE = nE[t];
    hipMemsetAsync(counts, 0, (size_t)2 * n * sizeof(int), stream);
    int eblocks = (nE[t] + 255) / 256;
    hist_kernel<<<dim3(eblocks, 2), 256, 0, stream>>>(ep, counts, n);
    scan_kernel<<<2, 256, 0, stream>>>(counts, offs, n);
    fill_kernel<<<dim3(eblocks, 2), 256, 0, stream>>>(ep, counts, csr_src, csr_w, n, MAXE);

    // gather: one wave per (node, rel)
    gather_csr<<<dim3((n + 3) / 4, 2), 256, 0, stream>>>(
        projb, projb + (size_t)m0 * 256, offs, csr_src, csr_w, MAXE, nbftb, n);

    // attention scores + softmax (faithful reshape semantics)
    e_dots<<<dim3((2 * n + 3) / 4), 256, 0, stream>>>(nbftb, selfb, (const float*)d_in[wb + 4], e_buf, n);
    att_kernel<<<dim3((n + 255) / 256), 256, 0, stream>>>(e_buf, att_buf, n);

    // fused [agg | self] @ wcat + bias
    final_gemm<<<dim3(4, (n + 63) / 64), 256, 0, stream>>>(
        nbftb, selfb, att_buf, (const float*)d_in[wb + 5], (const float*)d_in[wb + 6],
        (float*)d_out + out_off[t], n);
  }
}

// Round 4
// 667.808 us; speedup vs baseline: 6.8408x; 1.8997x over previous
//
#include <hip/hip_runtime.h>

namespace {

typedef short s16x8 __attribute__((ext_vector_type(8)));
typedef float f32x4 __attribute__((ext_vector_type(4)));

__device__ __forceinline__ float bf2f(unsigned short u) {
  return __uint_as_float(((unsigned)u) << 16);
}
__device__ __forceinline__ unsigned short f2bf(float f) {
  unsigned u = __float_as_uint(f);
  u += 0x7fffu + ((u >> 16) & 1u);
  return (unsigned short)(u >> 16);
}

struct Combine9 { const float* W[9]; const float* S[9]; float* O[9]; };

// Wc[512x256] = W[512x256] @ wsh[256x256], fp32
__global__ __launch_bounds__(256) void combine_weights(Combine9 a) {
  int combo = blockIdx.y;
  int r = blockIdx.x;
  int c = threadIdx.x;
  const float* W = a.W[combo];
  const float* S = a.S[combo];
  float acc = 0.f;
  #pragma unroll 4
  for (int k = 0; k < 256; ++k) acc = fmaf(W[r * 256 + k], S[k * 256 + c], acc);
  a.O[combo][r * 256 + c] = acc;
}

// fp32 [512][256] -> bf16 [256][512] (transposed, k-contiguous for MFMA B-frags)
struct Tc12 { const float* src[12]; unsigned short* dst[12]; };
__global__ __launch_bounds__(256) void transpose_cvt(Tc12 a) {
  int mat = blockIdx.z;
  const float* __restrict__ src = a.src[mat];
  unsigned short* __restrict__ dst = a.dst[mat];
  int r0 = blockIdx.y * 32, c0 = blockIdx.x * 32;
  __shared__ float T[32][33];
  int tx = threadIdx.x & 31, ty = threadIdx.x >> 5;
  #pragma unroll
  for (int j = 0; j < 4; ++j) {
    int r = ty + j * 8;
    T[r][tx] = src[(size_t)(r0 + r) * 256 + c0 + tx];
  }
  __syncthreads();
  #pragma unroll
  for (int j = 0; j < 4; ++j) {
    int c = ty + j * 8;
    dst[(size_t)(c0 + c) * 512 + r0 + tx] = f2bf(T[tx][c]);
  }
}

struct Cvt3 { const float* src[3]; unsigned short* dst[3]; int len[3]; };
__global__ __launch_bounds__(256) void cvt_x(Cvt3 a) {
  int t = blockIdx.y;
  int i = (blockIdx.x * 256 + threadIdx.x) * 8;
  if (i >= a.len[t]) return;
  const float4* s = (const float4*)(a.src[t] + i);
  float4 v0 = s[0], v1 = s[1];
  s16x8 o;
  o[0] = (short)f2bf(v0.x); o[1] = (short)f2bf(v0.y);
  o[2] = (short)f2bf(v0.z); o[3] = (short)f2bf(v0.w);
  o[4] = (short)f2bf(v1.x); o[5] = (short)f2bf(v1.y);
  o[6] = (short)f2bf(v1.z); o[7] = (short)f2bf(v1.w);
  *(s16x8*)(a.dst[t] + i) = o;
}

// C[M x 256](bf16) = A[M x 512](bf16) @ Bt[256 x 512]^T(bf16), 128x128 tile, MFMA 16x16x32
struct GemmB3 { const unsigned short* A[3]; const unsigned short* Bt[3]; unsigned short* C[3]; int M[3]; };
__global__ __launch_bounds__(256) void proj_mfma(GemmB3 g) {
  int z = blockIdx.z;
  int M = g.M[z];
  int row0 = blockIdx.y * 128;
  if (row0 >= M) return;
  int col0 = blockIdx.x * 128;
  const unsigned short* __restrict__ A = g.A[z];
  const unsigned short* __restrict__ Bt = g.Bt[z];
  unsigned short* __restrict__ C = g.C[z];
  __shared__ unsigned short As[128 * 40];  // pad 32->40 shorts: <=2-way conflicts (free)
  __shared__ unsigned short Bs[128 * 40];
  int tid = threadIdx.x, lane = tid & 63, w = tid >> 6;
  int quad = lane >> 4, m16 = lane & 15;
  f32x4 acc[2][8];
  #pragma unroll
  for (int r = 0; r < 2; ++r)
    #pragma unroll
    for (int c = 0; c < 8; ++c) acc[r][c] = (f32x4){0.f, 0.f, 0.f, 0.f};
  for (int k0 = 0; k0 < 512; k0 += 32) {
    #pragma unroll
    for (int i = 0; i < 2; ++i) {
      int ch = tid + i * 256;
      int m = ch >> 2, kk = (ch & 3) * 8;
      int gr = row0 + m;
      s16x8 v = {};
      if (gr < M) v = *(const s16x8*)(A + (size_t)gr * 512 + k0 + kk);
      *(s16x8*)&As[m * 40 + kk] = v;
      s16x8 b = *(const s16x8*)(Bt + (size_t)(col0 + m) * 512 + k0 + kk);
      *(s16x8*)&Bs[m * 40 + kk] = b;
    }
    __syncthreads();
    s16x8 af[2], bf[8];
    #pragma unroll
    for (int r = 0; r < 2; ++r)
      af[r] = *(const s16x8*)&As[(w * 32 + r * 16 + m16) * 40 + quad * 8];
    #pragma unroll
    for (int c = 0; c < 8; ++c)
      bf[c] = *(const s16x8*)&Bs[(c * 16 + m16) * 40 + quad * 8];
    #pragma unroll
    for (int r = 0; r < 2; ++r)
      #pragma unroll
      for (int c = 0; c < 8; ++c)
        acc[r][c] = __builtin_amdgcn_mfma_f32_16x16x32_bf16(af[r], bf[c], acc[r][c], 0, 0, 0);
    __syncthreads();
  }
  #pragma unroll
  for (int r = 0; r < 2; ++r)
    #pragma unroll
    for (int i = 0; i < 4; ++i) {
      int row = row0 + w * 32 + r * 16 + quad * 4 + i;
      if (row < M) {
        #pragma unroll
        for (int c = 0; c < 8; ++c)
          C[(size_t)row * 256 + col0 + c * 16 + m16] = f2bf(acc[r][c][i]);
      }
    }
}

struct Edges6 { const int* src[6]; const int* dst[6]; const float* w[6]; int nE[6]; int cbase[6]; };

__global__ __launch_bounds__(256) void hist_all(Edges6 ep, int* __restrict__ counts) {
  int rho = blockIdx.y;
  int e = blockIdx.x * 256 + threadIdx.x;
  if (e >= ep.nE[rho]) return;
  atomicAdd(&counts[ep.cbase[rho] + ep.dst[rho][e]], 1);
}

// hierarchical exclusive scan: scan1 (2048/block) -> scan2 (block sums) -> scan3 (add)
__global__ __launch_bounds__(256) void scan1(const int* __restrict__ cnt, int* __restrict__ out,
                                             int* __restrict__ part, int len) {
  __shared__ int sh[256];
  int base = blockIdx.x * 2048 + threadIdx.x * 8;
  int v[8];
  int s = 0;
  #pragma unroll
  for (int j = 0; j < 8; ++j) {
    int i = base + j;
    int x = (i < len) ? cnt[i] : 0;
    v[j] = s;
    s += x;
  }
  sh[threadIdx.x] = s;
  __syncthreads();
  for (int off = 1; off < 256; off <<= 1) {
    int t = (threadIdx.x >= off) ? sh[threadIdx.x - off] : 0;
    __syncthreads();
    sh[threadIdx.x] += t;
    __syncthreads();
  }
  int texcl = sh[threadIdx.x] - s;
  #pragma unroll
  for (int j = 0; j < 8; ++j) {
    int i = base + j;
    if (i < len) out[i] = texcl + v[j];
  }
  if (threadIdx.x == 255) part[blockIdx.x] = sh[255];
}

__global__ void scan2(int* __restrict__ part, int nb, int* __restrict__ total_out) {
  __shared__ int sh[64];
  int t = threadIdx.x;
  int v = (t < nb) ? part[t] : 0;
  sh[t] = v;
  __syncthreads();
  for (int off = 1; off < 64; off <<= 1) {
    int x = (t >= off) ? sh[t - off] : 0;
    __syncthreads();
    sh[t] += x;
    __syncthreads();
  }
  if (t < nb) part[t] = sh[t] - v;
  if (t == 63) *total_out = sh[63];
}

__global__ __launch_bounds__(256) void scan3(int* __restrict__ offs, int* __restrict__ cursor,
                                             const int* __restrict__ part, int len) {
  int i = blockIdx.x * 256 + threadIdx.x;
  if (i >= len) return;
  int v = offs[i] + part[i >> 11];
  offs[i] = v;
  cursor[i] = v;
}

__global__ __launch_bounds__(256) void fill_all(Edges6 ep, int* __restrict__ cursor,
                                                int* __restrict__ csr_src, float* __restrict__ csr_w) {
  int rho = blockIdx.y;
  int e = blockIdx.x * 256 + threadIdx.x;
  if (e >= ep.nE[rho]) return;
  int pos = atomicAdd(&cursor[ep.cbase[rho] + ep.dst[rho][e]], 1);
  csr_src[pos] = ep.src[rho][e];
  csr_w[pos] = ep.w[rho][e];
}

// one wave per (dst node, rel): register accumulate over edge bucket (bf16 proj rows)
__global__ __launch_bounds__(256) void gather_csr(const unsigned short* __restrict__ proj0,
                                                  const unsigned short* __restrict__ proj1,
                                                  const int* __restrict__ offs, int obase,
                                                  const int* __restrict__ csr_src,
                                                  const float* __restrict__ csr_w,
                                                  unsigned short* __restrict__ nbft, int n) {
  int rel = blockIdx.y;
  int d = blockIdx.x * 4 + (threadIdx.x >> 6);
  if (d >= n) return;
  int lane = threadIdx.x & 63;
  const unsigned short* __restrict__ proj = rel ? proj1 : proj0;
  const int* of = offs + obase + rel * n;
  int s0 = of[d], s1 = of[d + 1];
  float4 acc = make_float4(0.f, 0.f, 0.f, 0.f);
  for (int e = s0; e < s1; ++e) {
    int s = csr_src[e];
    float wt = csr_w[e];
    ushort4 u = *(const ushort4*)(proj + (size_t)s * 256 + (lane << 2));
    acc.x = fmaf(bf2f(u.x), wt, acc.x);
    acc.y = fmaf(bf2f(u.y), wt, acc.y);
    acc.z = fmaf(bf2f(u.z), wt, acc.z);
    acc.w = fmaf(bf2f(u.w), wt, acc.w);
  }
  ushort4 o;
  o.x = f2bf(acc.x); o.y = f2bf(acc.y); o.z = f2bf(acc.z); o.w = f2bf(acc.w);
  *(ushort4*)(nbft + ((size_t)rel * n + d) * 256 + (lane << 2)) = o;
}

// e_out[rel*n + i] = leaky(dot(nbft[rel][i], watt[0:256]) + dot(self[i], watt[256:512]))
// (reference concat order: [rel0 scores for all nodes; rel1 scores for all nodes])
__global__ __launch_bounds__(256) void e_dots(const unsigned short* __restrict__ nbft,
                                              const unsigned short* __restrict__ selfft,
                                              const float* __restrict__ watt,
                                              float* __restrict__ e_out, int n) {
  int idx = blockIdx.x * 4 + (threadIdx.x >> 6);
  if (idx >= 2 * n) return;
  int lane = threadIdx.x & 63;
  int i = idx < n ? idx : idx - n;
  ushort4 v  = *(const ushort4*)(nbft + (size_t)idx * 256 + (lane << 2));
  ushort4 sv = *(const ushort4*)(selfft + (size_t)i * 256 + (lane << 2));
  float4 wa = *(const float4*)(watt + (lane << 2));
  float4 wb = *(const float4*)(watt + 256 + (lane << 2));
  float sum = bf2f(v.x) * wa.x + bf2f(v.y) * wa.y + bf2f(v.z) * wa.z + bf2f(v.w) * wa.w +
              bf2f(sv.x) * wb.x + bf2f(sv.y) * wb.y + bf2f(sv.z) * wb.z + bf2f(sv.w) * wb.w;
  #pragma unroll
  for (int off = 32; off > 0; off >>= 1) sum += __shfl_down(sum, off, 64);
  if (lane == 0) e_out[idx] = sum > 0.f ? sum : 0.01f * sum;
}

// FAITHFUL reshape semantics: att pair i = softmax(e_flat[2i], e_flat[2i+1])
__global__ void att_kernel(const float* __restrict__ e_flat, float* __restrict__ att, int n) {
  int i = blockIdx.x * blockDim.x + threadIdx.x;
  if (i >= n) return;
  float f0 = e_flat[2 * i], f1 = e_flat[2 * i + 1];
  float m = fmaxf(f0, f1);
  float a = expf(f0 - m), b = expf(f1 - m);
  float inv = 1.f / (a + b);
  att[2 * i] = a * inv;
  att[2 * i + 1] = b * inv;
}

// out[M x 256](fp32) = [att0*nb0+att1*nb1 | self](bf16 on the fly) @ Wt^T + bias
__global__ __launch_bounds__(256) void final_mfma(const unsigned short* __restrict__ nbft,
                                                  const unsigned short* __restrict__ selfb,
                                                  const float* __restrict__ att,
                                                  const unsigned short* __restrict__ Wt,
                                                  const float* __restrict__ bias,
                                                  float* __restrict__ out, int M) {
  int row0 = blockIdx.y * 128;
  if (row0 >= M) return;
  int col0 = blockIdx.x * 128;
  __shared__ unsigned short As[128 * 40];
  __shared__ unsigned short Bs[128 * 40];
  int tid = threadIdx.x, lane = tid & 63, w = tid >> 6;
  int quad = lane >> 4, m16 = lane & 15;
  f32x4 acc[2][8];
  #pragma unroll
  for (int r = 0; r < 2; ++r)
    #pragma unroll
    for (int c = 0; c < 8; ++c) acc[r][c] = (f32x4){0.f, 0.f, 0.f, 0.f};
  for (int k0 = 0; k0 < 512; k0 += 32) {
    #pragma unroll
    for (int i = 0; i < 2; ++i) {
      int ch = tid + i * 256;
      int m = ch >> 2, kk = (ch & 3) * 8;
      int gr = row0 + m;
      int kg = k0 + kk;
      s16x8 v = {};
      if (gr < M) {
        if (kg < 256) {
          float a0 = att[2 * gr], a1 = att[2 * gr + 1];
          s16x8 u0 = *(const s16x8*)(nbft + (size_t)gr * 256 + kg);
          s16x8 u1 = *(const s16x8*)(nbft + ((size_t)M + gr) * 256 + kg);
          #pragma unroll
          for (int j = 0; j < 8; ++j)
            v[j] = (short)f2bf(fmaf(a0, bf2f((unsigned short)u0[j]),
                                    a1 * bf2f((unsigned short)u1[j])));
        } else {
          v = *(const s16x8*)(selfb + (size_t)gr * 256 + (kg - 256));
        }
      }
      *(s16x8*)&As[m * 40 + kk] = v;
      s16x8 b = *(const s16x8*)(Wt + (size_t)(col0 + m) * 512 + kg);
      *(s16x8*)&Bs[m * 40 + kk] = b;
    }
    __syncthreads();
    s16x8 af[2], bf[8];
    #pragma unroll
    for (int r = 0; r < 2; ++r)
      af[r] = *(const s16x8*)&As[(w * 32 + r * 16 + m16) * 40 + quad * 8];
    #pragma unroll
    for (int c = 0; c < 8; ++c)
      bf[c] = *(const s16x8*)&Bs[(c * 16 + m16) * 40 + quad * 8];
    #pragma unroll
    for (int r = 0; r < 2; ++r)
      #pragma unroll
      for (int c = 0; c < 8; ++c)
        acc[r][c] = __builtin_amdgcn_mfma_f32_16x16x32_bf16(af[r], bf[c], acc[r][c], 0, 0, 0);
    __syncthreads();
  }
  #pragma unroll
  for (int r = 0; r < 2; ++r)
    #pragma unroll
    for (int i = 0; i < 4; ++i) {
      int row = row0 + w * 32 + r * 16 + quad * 4 + i;
      if (row < M) {
        #pragma unroll
        for (int c = 0; c < 8; ++c) {
          int col = col0 + c * 16 + m16;
          out[(size_t)row * 256 + col] = acc[r][c][i] + bias[col];
        }
      }
    }
}

} // namespace

extern "C" void kernel_launch(void* const* d_in, const int* in_sizes, int n_in,
                              void* d_out, int out_size, void* d_ws, size_t ws_size,
                              hipStream_t stream) {
  (void)in_sizes; (void)n_in; (void)out_size; (void)ws_size;
  const float* x[3] = {(const float*)d_in[0], (const float*)d_in[1], (const float*)d_in[2]};

  // ---- workspace layout (bytes; total ~87.3 MB) ----
  char* p = (char*)d_ws;
  unsigned short* Wcbt = (unsigned short*)p;            p += (size_t)9 * 256 * 512 * 2;
  unsigned short* wcatbt = (unsigned short*)p;          p += (size_t)3 * 256 * 512 * 2;
  unsigned short* xb = (unsigned short*)p;              p += (size_t)35000 * 512 * 2;
  unsigned short* selfb = (unsigned short*)p;           p += (size_t)20000 * 256 * 2;
  unsigned short* dynb = (unsigned short*)p;            p += (size_t)14080000 * 2;
  float* e_buf = (float*)p;                             p += (size_t)40000 * 4;
  float* att_buf = (float*)p;                           p += (size_t)40000 * 4;
  int* counts = (int*)p;                                p += (size_t)70000 * 4;
  int* offs = (int*)p;                                  p += (size_t)70004 * 4;
  int* part = (int*)p;                                  p += 64 * 4;
  int* csr_src = (int*)p;                               p += (size_t)1120000 * 4;
  float* csr_w = (float*)p;                             p += (size_t)1120000 * 4;
  float* Wc_tmp = (float*)dynb;  // 4.72 MB, lives only until transpose_cvt

  const int n_of[3] = {20000, 10000, 5000};
  const int nbt[3][2] = {{1, 2}, {0, 2}, {0, 1}};
  const int ebase[3][2] = {{3, 6}, {9, 12}, {15, 18}};
  const int nE3[3] = {320000, 160000, 80000};
  const size_t xoff[3] = {0, (size_t)20000 * 512, (size_t)30000 * 512};
  const size_t out_off[3] = {0, (size_t)20000 * 256, (size_t)30000 * 256};

  // ---- combined weights (fp32): Wc = W @ wsh / ws @ wsh ----
  Combine9 c9;
  for (int t = 0; t < 3; ++t) {
    int wb = 21 + t * 7;
    const float* wsh = (const float*)d_in[wb + 3];
    c9.W[t * 3 + 0] = (const float*)d_in[wb + 0];
    c9.W[t * 3 + 1] = (const float*)d_in[wb + 1];
    c9.W[t * 3 + 2] = (const float*)d_in[wb + 2];
    for (int j = 0; j < 3; ++j) {
      c9.S[t * 3 + j] = wsh;
      c9.O[t * 3 + j] = Wc_tmp + (size_t)(t * 3 + j) * 512 * 256;
    }
  }
  combine_weights<<<dim3(512, 9), 256, 0, stream>>>(c9);

  // ---- transpose+convert 9 Wc + 3 wcat to bf16 [256][512] ----
  Tc12 tc;
  for (int i = 0; i < 9; ++i) {
    tc.src[i] = Wc_tmp + (size_t)i * 512 * 256;
    tc.dst[i] = Wcbt + (size_t)i * 256 * 512;
  }
  for (int t = 0; t < 3; ++t) {
    tc.src[9 + t] = (const float*)d_in[21 + t * 7 + 5];
    tc.dst[9 + t] = wcatbt + (size_t)t * 256 * 512;
  }
  transpose_cvt<<<dim3(8, 16, 12), 256, 0, stream>>>(tc);

  // ---- x -> bf16 ----
  Cvt3 cv;
  for (int t = 0; t < 3; ++t) {
    cv.src[t] = x[t];
    cv.dst[t] = xb + xoff[t];
    cv.len[t] = n_of[t] * 512;
  }
  cvt_x<<<dim3(5000, 3), 256, 0, stream>>>(cv);

  // ---- CSR build for all 6 relations ----
  Edges6 ep;
  const int cbase[6] = {0, 20000, 40000, 50000, 60000, 65000};
  for (int t = 0; t < 3; ++t)
    for (int r = 0; r < 2; ++r) {
      int rho = t * 2 + r, eb = ebase[t][r];
      ep.src[rho] = (const int*)d_in[eb];
      ep.dst[rho] = (const int*)d_in[eb + 1];
      ep.w[rho] = (const float*)d_in[eb + 2];
      ep.nE[rho] = nE3[t];
      ep.cbase[rho] = cbase[rho];
    }
  hipMemsetAsync(counts, 0, (size_t)70000 * 4, stream);
  hist_all<<<dim3(1250, 6), 256, 0, stream>>>(ep, counts);
  scan1<<<35, 256, 0, stream>>>(counts, offs, part, 70000);
  scan2<<<1, 64, 0, stream>>>(part, 35, offs + 70000);
  scan3<<<274, 256, 0, stream>>>(offs, counts, part, 70000);
  fill_all<<<dim3(1250, 6), 256, 0, stream>>>(ep, counts, csr_src, csr_w);

  // ---- per target type ----
  for (int t = 0; t < 3; ++t) {
    int n = n_of[t];
    int wb = 21 + t * 7;
    int nb0 = nbt[t][0], nb1 = nbt[t][1];
    int m0 = n_of[nb0], m1 = n_of[nb1];

    unsigned short* projb = dynb;
    unsigned short* nbftb = dynb + (size_t)(m0 + m1) * 256;

    GemmB3 g;
    g.A[0] = xb + xoff[nb0]; g.Bt[0] = Wcbt + (size_t)(t * 3 + 0) * 256 * 512; g.C[0] = projb;                    g.M[0] = m0;
    g.A[1] = xb + xoff[nb1]; g.Bt[1] = Wcbt + (size_t)(t * 3 + 1) * 256 * 512; g.C[1] = projb + (size_t)m0 * 256; g.M[1] = m1;
    g.A[2] = xb + xoff[t];   g.Bt[2] = Wcbt + (size_t)(t * 3 + 2) * 256 * 512; g.C[2] = selfb;                    g.M[2] = n;
    int maxM = m0 > m1 ? m0 : m1; if (n > maxM) maxM = n;
    proj_mfma<<<dim3(2, (maxM + 127) / 128, 3), 256, 0, stream>>>(g);

    gather_csr<<<dim3((n + 3) / 4, 2), 256, 0, stream>>>(
        projb, projb + (size_t)m0 * 256, offs, cbase[t * 2], csr_src, csr_w, nbftb, n);

    e_dots<<<dim3((2 * n + 3) / 4), 256, 0, stream>>>(
        nbftb, selfb, (const float*)d_in[wb + 4], e_buf, n);
    att_kernel<<<dim3((n + 255) / 256), 256, 0, stream>>>(e_buf, att_buf, n);

    final_mfma<<<dim3(2, (n + 127) / 128), 256, 0, stream>>>(
        nbftb, selfb, att_buf, wcatbt + (size_t)t * 256 * 512, (const float*)d_in[wb + 6],
        (float*)d_out + out_off[t], n);
  }
}

// Round 5
// 597.335 us; speedup vs baseline: 7.6478x; 1.1180x over previous
//
#include <hip/hip_runtime.h>

namespace {

typedef short s16x8 __attribute__((ext_vector_type(8)));
typedef float f32x4 __attribute__((ext_vector_type(4)));

__device__ __forceinline__ float bf2f(unsigned short u) {
  return __uint_as_float(((unsigned)u) << 16);
}
__device__ __forceinline__ unsigned short f2bf(float f) {
  unsigned u = __float_as_uint(f);
  u += 0x7fffu + ((u >> 16) & 1u);
  return (unsigned short)(u >> 16);
}

// fp32 [R][256] -> bf16 [256][R] (transposed). wsh: R=256, wcat: R=512.
struct Tc6 { const float* src[6]; unsigned short* dst[6]; int R[6]; };
__global__ __launch_bounds__(256) void transpose_cvt(Tc6 a) {
  int mat = blockIdx.z;
  int R = a.R[mat];
  int r0 = blockIdx.y * 32, c0 = blockIdx.x * 32;
  if (r0 >= R) return;
  const float* __restrict__ src = a.src[mat];
  unsigned short* __restrict__ dst = a.dst[mat];
  __shared__ float T[32][33];
  int tx = threadIdx.x & 31, ty = threadIdx.x >> 5;
  #pragma unroll
  for (int j = 0; j < 4; ++j) {
    int r = ty + j * 8;
    T[r][tx] = src[(size_t)(r0 + r) * 256 + c0 + tx];
  }
  __syncthreads();
  #pragma unroll
  for (int j = 0; j < 4; ++j) {
    int c = ty + j * 8;
    dst[(size_t)(c0 + c) * R + r0 + tx] = f2bf(T[tx][c]);
  }
}

// Wcbt[256x512] = wshT[256x256](bf16) @ W[512x256]^T(fp32, cvt on load)
// (Wc^T = wsh^T @ W^T; B-operand [N][K] k-contig == W row-major directly)
struct Comb9 { const unsigned short* A[9]; const float* B[9]; unsigned short* C[9]; };
__global__ __launch_bounds__(256) void combine_mfma(Comb9 g) {
  int z = blockIdx.z;
  const unsigned short* __restrict__ A = g.A[z];
  const float* __restrict__ B = g.B[z];
  unsigned short* __restrict__ C = g.C[z];
  int row0 = blockIdx.y * 128;   // 0,128 (M=256)
  int col0 = blockIdx.x * 128;   // 0..384 (N=512)
  __shared__ unsigned short As[128 * 40];
  __shared__ unsigned short Bs[128 * 40];
  int tid = threadIdx.x, lane = tid & 63, w = tid >> 6;
  int quad = lane >> 4, m16 = lane & 15;
  f32x4 acc[2][8];
  #pragma unroll
  for (int r = 0; r < 2; ++r)
    #pragma unroll
    for (int c = 0; c < 8; ++c) acc[r][c] = (f32x4){0.f, 0.f, 0.f, 0.f};
  for (int k0 = 0; k0 < 256; k0 += 32) {
    #pragma unroll
    for (int i = 0; i < 2; ++i) {
      int ch = tid + i * 256;
      int m = ch >> 2, kk = (ch & 3) * 8;
      *(s16x8*)&As[m * 40 + kk] = *(const s16x8*)(A + (size_t)(row0 + m) * 256 + k0 + kk);
      const float4* bp = (const float4*)(B + (size_t)(col0 + m) * 256 + k0 + kk);
      float4 b0 = bp[0], b1 = bp[1];
      s16x8 bv;
      bv[0] = (short)f2bf(b0.x); bv[1] = (short)f2bf(b0.y);
      bv[2] = (short)f2bf(b0.z); bv[3] = (short)f2bf(b0.w);
      bv[4] = (short)f2bf(b1.x); bv[5] = (short)f2bf(b1.y);
      bv[6] = (short)f2bf(b1.z); bv[7] = (short)f2bf(b1.w);
      *(s16x8*)&Bs[m * 40 + kk] = bv;
    }
    __syncthreads();
    s16x8 af[2], bf[8];
    #pragma unroll
    for (int r = 0; r < 2; ++r)
      af[r] = *(const s16x8*)&As[(w * 32 + r * 16 + m16) * 40 + quad * 8];
    #pragma unroll
    for (int c = 0; c < 8; ++c)
      bf[c] = *(const s16x8*)&Bs[(c * 16 + m16) * 40 + quad * 8];
    #pragma unroll
    for (int r = 0; r < 2; ++r)
      #pragma unroll
      for (int c = 0; c < 8; ++c)
        acc[r][c] = __builtin_amdgcn_mfma_f32_16x16x32_bf16(af[r], bf[c], acc[r][c], 0, 0, 0);
    __syncthreads();
  }
  #pragma unroll
  for (int r = 0; r < 2; ++r)
    #pragma unroll
    for (int i = 0; i < 4; ++i) {
      int row = row0 + w * 32 + r * 16 + quad * 4 + i;
      #pragma unroll
      for (int c = 0; c < 8; ++c)
        C[(size_t)row * 512 + col0 + c * 16 + m16] = f2bf(acc[r][c][i]);
    }
}

// C[M x 256](bf16) = A[M x 512](fp32, cvt on load) @ Bt[256 x 512]^T(bf16)
struct GemmB3 { const float* A[3]; const unsigned short* Bt[3]; unsigned short* C[3]; int M[3]; };
__global__ __launch_bounds__(256) void proj_mfma(GemmB3 g) {
  int z = blockIdx.z;
  int M = g.M[z];
  int row0 = blockIdx.y * 128;
  if (row0 >= M) return;
  int col0 = blockIdx.x * 128;
  const float* __restrict__ A = g.A[z];
  const unsigned short* __restrict__ Bt = g.Bt[z];
  unsigned short* __restrict__ C = g.C[z];
  __shared__ unsigned short As[128 * 40];
  __shared__ unsigned short Bs[128 * 40];
  int tid = threadIdx.x, lane = tid & 63, w = tid >> 6;
  int quad = lane >> 4, m16 = lane & 15;
  f32x4 acc[2][8];
  #pragma unroll
  for (int r = 0; r < 2; ++r)
    #pragma unroll
    for (int c = 0; c < 8; ++c) acc[r][c] = (f32x4){0.f, 0.f, 0.f, 0.f};
  for (int k0 = 0; k0 < 512; k0 += 32) {
    #pragma unroll
    for (int i = 0; i < 2; ++i) {
      int ch = tid + i * 256;
      int m = ch >> 2, kk = (ch & 3) * 8;
      int gr = row0 + m;
      s16x8 v = {};
      if (gr < M) {
        const float4* ap = (const float4*)(A + (size_t)gr * 512 + k0 + kk);
        float4 a0 = ap[0], a1 = ap[1];
        v[0] = (short)f2bf(a0.x); v[1] = (short)f2bf(a0.y);
        v[2] = (short)f2bf(a0.z); v[3] = (short)f2bf(a0.w);
        v[4] = (short)f2bf(a1.x); v[5] = (short)f2bf(a1.y);
        v[6] = (short)f2bf(a1.z); v[7] = (short)f2bf(a1.w);
      }
      *(s16x8*)&As[m * 40 + kk] = v;
      *(s16x8*)&Bs[m * 40 + kk] = *(const s16x8*)(Bt + (size_t)(col0 + m) * 512 + k0 + kk);
    }
    __syncthreads();
    s16x8 af[2], bf[8];
    #pragma unroll
    for (int r = 0; r < 2; ++r)
      af[r] = *(const s16x8*)&As[(w * 32 + r * 16 + m16) * 40 + quad * 8];
    #pragma unroll
    for (int c = 0; c < 8; ++c)
      bf[c] = *(const s16x8*)&Bs[(c * 16 + m16) * 40 + quad * 8];
    #pragma unroll
    for (int r = 0; r < 2; ++r)
      #pragma unroll
      for (int c = 0; c < 8; ++c)
        acc[r][c] = __builtin_amdgcn_mfma_f32_16x16x32_bf16(af[r], bf[c], acc[r][c], 0, 0, 0);
    __syncthreads();
  }
  #pragma unroll
  for (int r = 0; r < 2; ++r)
    #pragma unroll
    for (int i = 0; i < 4; ++i) {
      int row = row0 + w * 32 + r * 16 + quad * 4 + i;
      if (row < M) {
        #pragma unroll
        for (int c = 0; c < 8; ++c)
          C[(size_t)row * 256 + col0 + c * 16 + m16] = f2bf(acc[r][c][i]);
      }
    }
}

struct Edges6 { const int* src[6]; const int* dst[6]; const float* w[6]; int nE[6]; int cbase[6]; };

__global__ __launch_bounds__(256) void hist_all(Edges6 ep, int* __restrict__ counts) {
  int rho = blockIdx.y;
  int e = blockIdx.x * 256 + threadIdx.x;
  if (e >= ep.nE[rho]) return;
  atomicAdd(&counts[ep.cbase[rho] + ep.dst[rho][e]], 1);
}

__global__ __launch_bounds__(256) void scan1(const int* __restrict__ cnt, int* __restrict__ out,
                                             int* __restrict__ part, int len) {
  __shared__ int sh[256];
  int base = blockIdx.x * 2048 + threadIdx.x * 8;
  int v[8];
  int s = 0;
  #pragma unroll
  for (int j = 0; j < 8; ++j) {
    int i = base + j;
    int x = (i < len) ? cnt[i] : 0;
    v[j] = s;
    s += x;
  }
  sh[threadIdx.x] = s;
  __syncthreads();
  for (int off = 1; off < 256; off <<= 1) {
    int t = (threadIdx.x >= off) ? sh[threadIdx.x - off] : 0;
    __syncthreads();
    sh[threadIdx.x] += t;
    __syncthreads();
  }
  int texcl = sh[threadIdx.x] - s;
  #pragma unroll
  for (int j = 0; j < 8; ++j) {
    int i = base + j;
    if (i < len) out[i] = texcl + v[j];
  }
  if (threadIdx.x == 255) part[blockIdx.x] = sh[255];
}

__global__ void scan2(int* __restrict__ part, int nb, int* __restrict__ total_out) {
  __shared__ int sh[64];
  int t = threadIdx.x;
  int v = (t < nb) ? part[t] : 0;
  sh[t] = v;
  __syncthreads();
  for (int off = 1; off < 64; off <<= 1) {
    int x = (t >= off) ? sh[t - off] : 0;
    __syncthreads();
    sh[t] += x;
    __syncthreads();
  }
  if (t < nb) part[t] = sh[t] - v;
  if (t == 63) *total_out = sh[63];
}

__global__ __launch_bounds__(256) void scan3(int* __restrict__ offs, int* __restrict__ cursor,
                                             const int* __restrict__ part, int len) {
  int i = blockIdx.x * 256 + threadIdx.x;
  if (i >= len) return;
  int v = offs[i] + part[i >> 11];
  offs[i] = v;
  cursor[i] = v;
}

__global__ __launch_bounds__(256) void fill_all(Edges6 ep, int* __restrict__ cursor,
                                                int* __restrict__ csr_src, float* __restrict__ csr_w) {
  int rho = blockIdx.y;
  int e = blockIdx.x * 256 + threadIdx.x;
  if (e >= ep.nE[rho]) return;
  int pos = atomicAdd(&cursor[ep.cbase[rho] + ep.dst[rho][e]], 1);
  csr_src[pos] = ep.src[rho][e];
  csr_w[pos] = ep.w[rho][e];
}

// one wave per (dst node, rel); 2 edges in flight (half-wave each, 16B/lane),
// xor-shuffle merge of the two half-accumulators at the end.
__global__ __launch_bounds__(256) void gather_csr(const unsigned short* __restrict__ proj0,
                                                  const unsigned short* __restrict__ proj1,
                                                  const int* __restrict__ offs, int obase,
                                                  const int* __restrict__ csr_src,
                                                  const float* __restrict__ csr_w,
                                                  unsigned short* __restrict__ nbft, int n) {
  int rel = blockIdx.y;
  int d = blockIdx.x * 4 + (threadIdx.x >> 6);
  if (d >= n) return;
  int lane = threadIdx.x & 63, half = lane >> 5, l32 = lane & 31;
  const unsigned short* __restrict__ proj = rel ? proj1 : proj0;
  const int* of = offs + obase + rel * n;
  int s0 = of[d], s1 = of[d + 1];
  float acc[8] = {};
  for (int e = s0 + half; e < s1; e += 2) {
    int s = csr_src[e];
    float wt = csr_w[e];
    s16x8 u = *(const s16x8*)(proj + (size_t)s * 256 + l32 * 8);
    #pragma unroll
    for (int j = 0; j < 8; ++j) acc[j] = fmaf(bf2f((unsigned short)u[j]), wt, acc[j]);
  }
  #pragma unroll
  for (int j = 0; j < 8; ++j) acc[j] += __shfl(acc[j], lane ^ 32, 64);
  if (half == 0) {
    s16x8 o;
    #pragma unroll
    for (int j = 0; j < 8; ++j) o[j] = (short)f2bf(acc[j]);
    *(s16x8*)(nbft + ((size_t)rel * n + d) * 256 + l32 * 8) = o;
  }
}

// fused: e[idx] = dot-scores (idx in [0,2n), concat order [rel0; rel1]), then
// FAITHFUL reshape(n,2) softmax over adjacent pairs (2i,2i+1). n, 2n divisible by 4,
// so both pairs complete inside each 4-wave block.
__global__ __launch_bounds__(256) void e_att(const unsigned short* __restrict__ nbft,
                                             const unsigned short* __restrict__ selfft,
                                             const float* __restrict__ watt,
                                             float* __restrict__ att, int n) {
  int wv = threadIdx.x >> 6;
  int idx = blockIdx.x * 4 + wv;
  int lane = threadIdx.x & 63;
  __shared__ float ev[4];
  float sum = 0.f;
  if (idx < 2 * n) {
    int i = idx < n ? idx : idx - n;
    ushort4 v  = *(const ushort4*)(nbft + (size_t)idx * 256 + (lane << 2));
    ushort4 sv = *(const ushort4*)(selfft + (size_t)i * 256 + (lane << 2));
    float4 wa = *(const float4*)(watt + (lane << 2));
    float4 wb = *(const float4*)(watt + 256 + (lane << 2));
    sum = bf2f(v.x) * wa.x + bf2f(v.y) * wa.y + bf2f(v.z) * wa.z + bf2f(v.w) * wa.w +
          bf2f(sv.x) * wb.x + bf2f(sv.y) * wb.y + bf2f(sv.z) * wb.z + bf2f(sv.w) * wb.w;
    #pragma unroll
    for (int off = 32; off > 0; off >>= 1) sum += __shfl_down(sum, off, 64);
  }
  if (lane == 0) ev[wv] = sum;
  __syncthreads();
  if (threadIdx.x < 2) {
    int base = blockIdx.x * 4 + threadIdx.x * 2;  // e_flat index of pair start
    if (base < 2 * n) {
      float f0 = ev[threadIdx.x * 2], f1 = ev[threadIdx.x * 2 + 1];
      f0 = f0 > 0.f ? f0 : 0.01f * f0;
      f1 = f1 > 0.f ? f1 : 0.01f * f1;
      float m = fmaxf(f0, f1);
      float a = expf(f0 - m), b = expf(f1 - m);
      float inv = 1.f / (a + b);
      att[base] = a * inv;
      att[base + 1] = b * inv;
    }
  }
}

// out[M x 256](fp32) = [att0*nb0+att1*nb1 | self](bf16 on the fly) @ Wt^T + bias
__global__ __launch_bounds__(256) void final_mfma(const unsigned short* __restrict__ nbft,
                                                  const unsigned short* __restrict__ selfb,
                                                  const float* __restrict__ att,
                                                  const unsigned short* __restrict__ Wt,
                                                  const float* __restrict__ bias,
                                                  float* __restrict__ out, int M) {
  int row0 = blockIdx.y * 128;
  if (row0 >= M) return;
  int col0 = blockIdx.x * 128;
  __shared__ unsigned short As[128 * 40];
  __shared__ unsigned short Bs[128 * 40];
  int tid = threadIdx.x, lane = tid & 63, w = tid >> 6;
  int quad = lane >> 4, m16 = lane & 15;
  f32x4 acc[2][8];
  #pragma unroll
  for (int r = 0; r < 2; ++r)
    #pragma unroll
    for (int c = 0; c < 8; ++c) acc[r][c] = (f32x4){0.f, 0.f, 0.f, 0.f};
  for (int k0 = 0; k0 < 512; k0 += 32) {
    #pragma unroll
    for (int i = 0; i < 2; ++i) {
      int ch = tid + i * 256;
      int m = ch >> 2, kk = (ch & 3) * 8;
      int gr = row0 + m;
      int kg = k0 + kk;
      s16x8 v = {};
      if (gr < M) {
        if (kg < 256) {
          float a0 = att[2 * gr], a1 = att[2 * gr + 1];
          s16x8 u0 = *(const s16x8*)(nbft + (size_t)gr * 256 + kg);
          s16x8 u1 = *(const s16x8*)(nbft + ((size_t)M + gr) * 256 + kg);
          #pragma unroll
          for (int j = 0; j < 8; ++j)
            v[j] = (short)f2bf(fmaf(a0, bf2f((unsigned short)u0[j]),
                                    a1 * bf2f((unsigned short)u1[j])));
        } else {
          v = *(const s16x8*)(selfb + (size_t)gr * 256 + (kg - 256));
        }
      }
      *(s16x8*)&As[m * 40 + kk] = v;
      *(s16x8*)&Bs[m * 40 + kk] = *(const s16x8*)(Wt + (size_t)(col0 + m) * 512 + kg);
    }
    __syncthreads();
    s16x8 af[2], bf[8];
    #pragma unroll
    for (int r = 0; r < 2; ++r)
      af[r] = *(const s16x8*)&As[(w * 32 + r * 16 + m16) * 40 + quad * 8];
    #pragma unroll
    for (int c = 0; c < 8; ++c)
      bf[c] = *(const s16x8*)&Bs[(c * 16 + m16) * 40 + quad * 8];
    #pragma unroll
    for (int r = 0; r < 2; ++r)
      #pragma unroll
      for (int c = 0; c < 8; ++c)
        acc[r][c] = __builtin_amdgcn_mfma_f32_16x16x32_bf16(af[r], bf[c], acc[r][c], 0, 0, 0);
    __syncthreads();
  }
  #pragma unroll
  for (int r = 0; r < 2; ++r)
    #pragma unroll
    for (int i = 0; i < 4; ++i) {
      int row = row0 + w * 32 + r * 16 + quad * 4 + i;
      if (row < M) {
        #pragma unroll
        for (int c = 0; c < 8; ++c) {
          int col = col0 + c * 16 + m16;
          out[(size_t)row * 256 + col] = acc[r][c][i] + bias[col];
        }
      }
    }
}

} // namespace

extern "C" void kernel_launch(void* const* d_in, const int* in_sizes, int n_in,
                              void* d_out, int out_size, void* d_ws, size_t ws_size,
                              hipStream_t stream) {
  (void)in_sizes; (void)n_in; (void)out_size; (void)ws_size;
  const float* x[3] = {(const float*)d_in[0], (const float*)d_in[1], (const float*)d_in[2]};

  // ---- workspace layout (~51.6 MB) ----
  char* p = (char*)d_ws;
  unsigned short* wshT = (unsigned short*)p;            p += (size_t)3 * 256 * 256 * 2;
  unsigned short* Wcbt = (unsigned short*)p;            p += (size_t)9 * 256 * 512 * 2;
  unsigned short* wcatbt = (unsigned short*)p;          p += (size_t)3 * 256 * 512 * 2;
  unsigned short* selfb = (unsigned short*)p;           p += (size_t)20000 * 256 * 2;
  unsigned short* dynb = (unsigned short*)p;            p += (size_t)14080000 * 2;
  float* att_buf = (float*)p;                           p += (size_t)40000 * 4;
  int* counts = (int*)p;                                p += (size_t)70000 * 4;
  int* offs = (int*)p;                                  p += (size_t)70004 * 4;
  int* part = (int*)p;                                  p += 64 * 4;
  int* csr_src = (int*)p;                               p += (size_t)1120000 * 4;
  float* csr_w = (float*)p;                             p += (size_t)1120000 * 4;

  const int n_of[3] = {20000, 10000, 5000};
  const int nbt[3][2] = {{1, 2}, {0, 2}, {0, 1}};
  const int ebase[3][2] = {{3, 6}, {9, 12}, {15, 18}};
  const int nE3[3] = {320000, 160000, 80000};
  const size_t out_off[3] = {0, (size_t)20000 * 256, (size_t)30000 * 256};

  // ---- transpose+cvt: 3 wsh [256][256] -> wshT, 3 wcat [512][256] -> wcatbt ----
  Tc6 tc;
  for (int t = 0; t < 3; ++t) {
    tc.src[t] = (const float*)d_in[21 + t * 7 + 3];   // wsh_t
    tc.dst[t] = wshT + (size_t)t * 256 * 256;
    tc.R[t] = 256;
    tc.src[3 + t] = (const float*)d_in[21 + t * 7 + 5];  // wcat_t
    tc.dst[3 + t] = wcatbt + (size_t)t * 256 * 512;
    tc.R[3 + t] = 512;
  }
  transpose_cvt<<<dim3(8, 16, 6), 256, 0, stream>>>(tc);

  // ---- combined weights via MFMA: Wcbt[combo] = (W_combo @ wsh_t)^T ----
  Comb9 c9;
  for (int t = 0; t < 3; ++t) {
    int wb = 21 + t * 7;
    for (int j = 0; j < 3; ++j) {
      int combo = t * 3 + j;
      c9.A[combo] = wshT + (size_t)t * 256 * 256;
      c9.B[combo] = (const float*)d_in[wb + j];   // W_t_nb0, W_t_nb1, ws_t
      c9.C[combo] = Wcbt + (size_t)combo * 256 * 512;
    }
  }
  combine_mfma<<<dim3(4, 2, 9), 256, 0, stream>>>(c9);

  // ---- CSR build for all 6 relations ----
  Edges6 ep;
  const int cbase[6] = {0, 20000, 40000, 50000, 60000, 65000};
  for (int t = 0; t < 3; ++t)
    for (int r = 0; r < 2; ++r) {
      int rho = t * 2 + r, eb = ebase[t][r];
      ep.src[rho] = (const int*)d_in[eb];
      ep.dst[rho] = (const int*)d_in[eb + 1];
      ep.w[rho] = (const float*)d_in[eb + 2];
      ep.nE[rho] = nE3[t];
      ep.cbase[rho] = cbase[rho];
    }
  hipMemsetAsync(counts, 0, (size_t)70000 * 4, stream);
  hist_all<<<dim3(1250, 6), 256, 0, stream>>>(ep, counts);
  scan1<<<35, 256, 0, stream>>>(counts, offs, part, 70000);
  scan2<<<1, 64, 0, stream>>>(part, 35, offs + 70000);
  scan3<<<274, 256, 0, stream>>>(offs, counts, part, 70000);
  fill_all<<<dim3(1250, 6), 256, 0, stream>>>(ep, counts, csr_src, csr_w);

  // ---- per target type ----
  for (int t = 0; t < 3; ++t) {
    int n = n_of[t];
    int wb = 21 + t * 7;
    int nb0 = nbt[t][0], nb1 = nbt[t][1];
    int m0 = n_of[nb0], m1 = n_of[nb1];

    unsigned short* projb = dynb;
    unsigned short* nbftb = dynb + (size_t)(m0 + m1) * 256;

    GemmB3 g;
    g.A[0] = x[nb0]; g.Bt[0] = Wcbt + (size_t)(t * 3 + 0) * 256 * 512; g.C[0] = projb;                    g.M[0] = m0;
    g.A[1] = x[nb1]; g.Bt[1] = Wcbt + (size_t)(t * 3 + 1) * 256 * 512; g.C[1] = projb + (size_t)m0 * 256; g.M[1] = m1;
    g.A[2] = x[t];   g.Bt[2] = Wcbt + (size_t)(t * 3 + 2) * 256 * 512; g.C[2] = selfb;                    g.M[2] = n;
    int maxM = m0 > m1 ? m0 : m1; if (n > maxM) maxM = n;
    proj_mfma<<<dim3(2, (maxM + 127) / 128, 3), 256, 0, stream>>>(g);

    gather_csr<<<dim3((n + 3) / 4, 2), 256, 0, stream>>>(
        projb, projb + (size_t)m0 * 256, offs, cbase[t * 2], csr_src, csr_w, nbftb, n);

    e_att<<<dim3((2 * n) / 4), 256, 0, stream>>>(
        nbftb, selfb, (const float*)d_in[wb + 4], att_buf, n);

    final_mfma<<<dim3(2, (n + 127) / 128), 256, 0, stream>>>(
        nbftb, selfb, att_buf, wcatbt + (size_t)t * 256 * 512, (const float*)d_in[wb + 6],
        (float*)d_out + out_off[t], n);
  }
}